// Round 1
// baseline (683.684 us; speedup 1.0000x reference)
//
#include <hip/hip_runtime.h>
#include <math.h>

#define NEGV (-1e9f)

// Shapes: BS=2048, L=100, D=256, N=16, K=32
// rows M = BS*L = 204800; K1 tiles 64 rows/block -> 3200 blocks

struct P1 { float As[64][36]; float Bs[32][258]; };   // 9216 + 33024 B
struct P2 { float Pj[64][260]; float Cs[32][36]; };   // 66560 + 4608 B
union U1 { P1 p1; P2 p2; };                            // 71168 B -> 2 blocks/CU

__global__ __launch_bounds__(256, 2)
void k_proj_logits(const float* __restrict__ hist, const float* __restrict__ W,
                   const float* __restrict__ cc, float* __restrict__ logits)
{
    __shared__ U1 u;
    const int tid = threadIdx.x;
    const int tc = tid & 15;   // e-group
    const int tr = tid >> 4;   // row-group
    const int r0 = tr * 4;
    const int rowBase = blockIdx.x * 64;

    float acc[4][16];
    #pragma unroll
    for (int i = 0; i < 4; ++i)
        #pragma unroll
        for (int j = 0; j < 16; ++j) acc[i][j] = 0.0f;

    for (int kt = 0; kt < 256; kt += 32) {
        // A tile: 64 rows x 32 d-cols (coalesced float4)
        #pragma unroll
        for (int s = 0; s < 2; ++s) {
            int idx = tid + s * 256;
            int ar = idx >> 3;
            int ac = (idx & 7) * 4;
            float4 v = *(const float4*)&hist[(size_t)(rowBase + ar) * 256 + kt + ac];
            *(float4*)&u.p1.As[ar][ac] = v;
        }
        // B tile: W[e][kt..kt+31] stored transposed [k][e]
        #pragma unroll
        for (int p = 0; p < 8; ++p) {
            int e = (tid >> 3) + p * 32;
            int c4 = (tid & 7) * 4;
            float4 v = *(const float4*)&W[(size_t)e * 256 + kt + c4];
            u.p1.Bs[c4 + 0][e] = v.x;
            u.p1.Bs[c4 + 1][e] = v.y;
            u.p1.Bs[c4 + 2][e] = v.z;
            u.p1.Bs[c4 + 3][e] = v.w;
        }
        __syncthreads();
        #pragma unroll 4
        for (int k = 0; k < 32; ++k) {
            float a0 = u.p1.As[r0 + 0][k];
            float a1 = u.p1.As[r0 + 1][k];
            float a2 = u.p1.As[r0 + 2][k];
            float a3 = u.p1.As[r0 + 3][k];
            const float2* brow = (const float2*)u.p1.Bs[k];
            #pragma unroll
            for (int jj = 0; jj < 8; ++jj) {
                float2 bv = brow[tc + 16 * jj];   // e = 2tc + 32jj (+1)
                acc[0][2*jj]   += a0 * bv.x;  acc[0][2*jj+1] += a0 * bv.y;
                acc[1][2*jj]   += a1 * bv.x;  acc[1][2*jj+1] += a1 * bv.y;
                acc[2][2*jj]   += a2 * bv.x;  acc[2][2*jj+1] += a2 * bv.y;
                acc[3][2*jj]   += a3 * bv.x;  acc[3][2*jj+1] += a3 * bv.y;
            }
        }
        __syncthreads();
    }

    // tanh + store proj tile to LDS (union reuse; all reads of As/Bs done)
    #pragma unroll
    for (int i = 0; i < 4; ++i) {
        #pragma unroll
        for (int j = 0; j < 16; ++j) {
            int e = 32 * (j >> 1) + 2 * tc + (j & 1);
            u.p2.Pj[r0 + i][e] = tanhf(acc[i][j]);
        }
    }
    __syncthreads();

    // logits[k][l] = sum_e Pj[l][e] * cc[k][e]
    float lacc[8];
    #pragma unroll
    for (int j = 0; j < 8; ++j) lacc[j] = 0.0f;
    const int lk = tid >> 3;   // 0..31
    const int lg = tid & 7;    // 0..7
    for (int et = 0; et < 8; ++et) {
        {
            int k2 = tid >> 3;
            int c4 = (tid & 7) * 4;
            float4 v = *(const float4*)&cc[(size_t)k2 * 256 + et * 32 + c4];
            *(float4*)&u.p2.Cs[k2][c4] = v;
        }
        __syncthreads();
        #pragma unroll
        for (int eq = 0; eq < 8; ++eq) {
            float4 c4 = *(const float4*)&u.p2.Cs[lk][eq * 4];
            #pragma unroll
            for (int jl = 0; jl < 8; ++jl) {
                float4 p4 = *(const float4*)&u.p2.Pj[lg + 8 * jl][et * 32 + eq * 4];
                lacc[jl] += p4.x * c4.x + p4.y * c4.y + p4.z * c4.z + p4.w * c4.w;
            }
        }
        __syncthreads();
    }
    #pragma unroll
    for (int jl = 0; jl < 8; ++jl) {
        int r = rowBase + lg + 8 * jl;
        int b = r / 100;
        int l = r - b * 100;
        logits[(size_t)b * 3200 + lk * 100 + l] = lacc[jl];
    }
}

// K2: per-batch fused mask+softmax -> interests -> aw -> top-k -> user
__global__ __launch_bounds__(256, 2)
void k_attn(const float* __restrict__ hist, const float* __restrict__ cand,
            const int* __restrict__ numi, const int* __restrict__ catc,
            const float* __restrict__ logits, float* __restrict__ out)
{
    __shared__ float wT[100][36];     // weights transposed [l][k]
    __shared__ float ints[32][260];   // interests [k][d]
    __shared__ float cands[16][260];  // cand [n][d]
    __shared__ float aws[16][36];
    __shared__ float maw[16][36];

    const int tid = threadIdx.x;
    const int b = blockIdx.x;
    const int num = numi[b];

    // load logits (transposed into wT) and cand tile
    for (int idx = tid; idx < 3200; idx += 256) {
        int k = idx / 100;
        int l = idx - k * 100;
        wT[l][k] = logits[(size_t)b * 3200 + idx];
    }
    #pragma unroll
    for (int s = 0; s < 4; ++s) {
        int idx = tid + s * 256;
        int n = idx >> 6;
        int c4 = (idx & 63) * 4;
        *(float4*)&cands[n][c4] = *(const float4*)&cand[((size_t)b * 16 + n) * 256 + c4];
    }
    __syncthreads();

    // masked softmax over l, 8 lanes per k-row
    {
        const int k = tid >> 3;
        const int lg = tid & 7;
        const bool valid = k < num;
        float vals[13];
        float m = -INFINITY;
        #pragma unroll
        for (int i = 0; i < 13; ++i) {
            int l = lg + 8 * i;
            if (l < 100) {
                float v = valid ? wT[l][k] : NEGV;
                vals[i] = v;
                m = fmaxf(m, v);
            }
        }
        #pragma unroll
        for (int off = 1; off < 8; off <<= 1)
            m = fmaxf(m, __shfl_xor(m, off, 8));
        float s = 0.0f;
        #pragma unroll
        for (int i = 0; i < 13; ++i) {
            int l = lg + 8 * i;
            if (l < 100) {
                float e = expf(vals[i] - m);
                s += e;
                wT[l][k] = e;
            }
        }
        #pragma unroll
        for (int off = 1; off < 8; off <<= 1)
            s += __shfl_xor(s, off, 8);
        float inv = 1.0f / s;
        #pragma unroll
        for (int i = 0; i < 13; ++i) {
            int l = lg + 8 * i;
            if (l < 100) wT[l][k] *= inv;
        }
    }
    __syncthreads();

    // interests[k][d] = sum_l w[k][l] * hist[b][l][d]; thread owns d
    {
        const int d = tid;
        float acc[32];
        #pragma unroll
        for (int k = 0; k < 32; ++k) acc[k] = 0.0f;
        for (int l = 0; l < 100; ++l) {
            float h = hist[((size_t)b * 100 + l) * 256 + d];
            const float4* wrow = (const float4*)wT[l];
            #pragma unroll
            for (int kq = 0; kq < 8; ++kq) {
                float4 w4 = wrow[kq];
                acc[4 * kq + 0] += w4.x * h;
                acc[4 * kq + 1] += w4.y * h;
                acc[4 * kq + 2] += w4.z * h;
                acc[4 * kq + 3] += w4.w * h;
            }
        }
        #pragma unroll
        for (int k = 0; k < 32; ++k) ints[k][d] = acc[k];
    }
    __syncthreads();

    // aw[n][k] = interests[k] . cand[n]; thread does (n1,k) and (n1+8,k)
    {
        const int k = tid & 31;
        const int n1 = tid >> 5;   // 0..7
        float s1 = 0.0f, s2 = 0.0f;
        const float4* irow = (const float4*)ints[k];
        const float4* c1 = (const float4*)cands[n1];
        const float4* c2 = (const float4*)cands[n1 + 8];
        for (int q = 0; q < 64; ++q) {
            float4 iv = irow[q];
            float4 a = c1[q];
            float4 c = c2[q];
            s1 += iv.x * a.x + iv.y * a.y + iv.z * a.z + iv.w * a.w;
            s2 += iv.x * c.x + iv.y * c.y + iv.z * c.z + iv.w * c.w;
        }
        aws[n1][k] = s1;
        aws[n1 + 8][k] = s2;
    }
    __syncthreads();

    // stable descending rank + dyn_K mask
    {
        int c = catc[b];
        int dynK = 32 - __clz(2 * c - 1);   // = clip(ceil(log2(2c)),1,32) for c in [1,20]
        const int k = tid & 31;
        const int n1 = tid >> 5;
        #pragma unroll
        for (int h = 0; h < 2; ++h) {
            int n = n1 + 8 * h;
            float a = aws[n][k];
            int cnt = 0;
            #pragma unroll
            for (int j = 0; j < 32; ++j) {
                float aj = aws[n][j];
                cnt += (aj > a) || (aj == a && j < k);
            }
            maw[n][k] = (cnt < dynK) ? a : 0.0f;
        }
    }
    __syncthreads();

    // user[n][d] = sum_k maw[n][k] * interests[k][d]
    {
        const int dd = tid & 63;   // float4 group of d
        const int ng = tid >> 6;   // 0..3 -> n = 4ng..4ng+3
        float4 acc4[4];
        #pragma unroll
        for (int nn = 0; nn < 4; ++nn) { acc4[nn].x = acc4[nn].y = acc4[nn].z = acc4[nn].w = 0.0f; }
        for (int k = 0; k < 32; ++k) {
            float4 iv = *(const float4*)&ints[k][4 * dd];
            #pragma unroll
            for (int nn = 0; nn < 4; ++nn) {
                float m = maw[4 * ng + nn][k];
                acc4[nn].x += m * iv.x;
                acc4[nn].y += m * iv.y;
                acc4[nn].z += m * iv.z;
                acc4[nn].w += m * iv.w;
            }
        }
        #pragma unroll
        for (int nn = 0; nn < 4; ++nn) {
            *(float4*)&out[((size_t)b * 16 + 4 * ng + nn) * 256 + 4 * dd] = acc4[nn];
        }
    }
}

extern "C" void kernel_launch(void* const* d_in, const int* in_sizes, int n_in,
                              void* d_out, int out_size, void* d_ws, size_t ws_size,
                              hipStream_t stream) {
    const float* hist = (const float*)d_in[0];
    // d_in[1] = history_mask (unused by reference)
    const float* cand = (const float*)d_in[2];
    const int*   numi = (const int*)d_in[3];
    const int*   catc = (const int*)d_in[4];
    const float* W    = (const float*)d_in[5];
    const float* cc   = (const float*)d_in[6];
    float* out = (float*)d_out;
    float* logits = (float*)d_ws;   // 2048*32*100*4 = 26,214,400 B

    k_proj_logits<<<3200, 256, 0, stream>>>(hist, W, cc, logits);
    k_attn<<<2048, 256, 0, stream>>>(hist, cand, numi, catc, logits, out);
}

// Round 2
// 636.493 us; speedup vs baseline: 1.0741x; 1.0741x over previous
//
#include <hip/hip_runtime.h>
#include <math.h>

#define NEGV (-1e9f)

// Shapes: BS=2048, L=100, D=256, N=16, K=32
// K1: rows M = BS*L = 204800, BM=128 -> 1600 blocks, 256 threads
// thread tile: 8 rows x 16 e-cols (acc 128 regs)
// rows owned: tr + 16*i (i=0..7), tr = tid>>4
// e owned:    2*tc + 32*jj + b (jj=0..7, b=0..1), tc = tid&15

struct Pm { float At[32][129]; float Bs[32][258]; };   // 16516 + 33024 B = 49540
struct Pe { float Pj[64][260]; float Cs[32][36]; };    // 66560 + 4608  B = 71168
union  U  { Pm m; Pe e; };                             // 71168 B -> 2 blocks/CU

__device__ inline float tanh_fast(float x) {
    // tanh(x) = 1 - 2/(exp(2x)+1); exp(2x)=inf -> 1, =0 -> -1 (no NaN)
    float t = __expf(2.0f * x);
    float r = __builtin_amdgcn_rcpf(t + 1.0f);
    return fmaf(-2.0f, r, 1.0f);
}

__global__ __launch_bounds__(256, 2)
void k_proj_logits(const float* __restrict__ hist, const float* __restrict__ W,
                   const float* __restrict__ cc, float* __restrict__ logits)
{
    __shared__ U u;
    const int tid = threadIdx.x;
    const int tr = tid >> 4;    // 0..15
    const int tc = tid & 15;    // 0..15
    const size_t rowBase = (size_t)blockIdx.x * 128;

    float acc[8][16];
    #pragma unroll
    for (int i = 0; i < 8; ++i)
        #pragma unroll
        for (int j = 0; j < 16; ++j) acc[i][j] = 0.0f;

    // global-load index precompute
    const int aRow = tid >> 1;            // unused pattern below; keep simple
    // A stage: idx = tid + s*256, s=0..3: row = idx>>1? -> use: row = idx>>3? No:
    // 128 rows x 8 float4-cols = 1024 float4 / 256 thr = 4 each.
    // idx = tid + s*256 -> row = idx>>3 (0..127), c4 = (idx&7)*4

    float4 aReg[4], bReg[8];

    // prefetch k-tile 0
    #pragma unroll
    for (int s = 0; s < 4; ++s) {
        int idx = tid + s * 256;
        int row = idx >> 3;
        int c4 = (idx & 7) * 4;
        aReg[s] = *(const float4*)&hist[(rowBase + row) * 256 + c4];
    }
    #pragma unroll
    for (int p = 0; p < 8; ++p) {
        int e = (tid >> 3) + p * 32;
        int c4 = (tid & 7) * 4;
        bReg[p] = *(const float4*)&W[(size_t)e * 256 + c4];
    }

    for (int kt = 0; kt < 256; kt += 32) {
        // commit staged regs to LDS (transposed)
        #pragma unroll
        for (int s = 0; s < 4; ++s) {
            int idx = tid + s * 256;
            int row = idx >> 3;
            int c4 = (idx & 7) * 4;
            u.m.At[c4 + 0][row] = aReg[s].x;
            u.m.At[c4 + 1][row] = aReg[s].y;
            u.m.At[c4 + 2][row] = aReg[s].z;
            u.m.At[c4 + 3][row] = aReg[s].w;
        }
        #pragma unroll
        for (int p = 0; p < 8; ++p) {
            int e = (tid >> 3) + p * 32;
            int c4 = (tid & 7) * 4;
            u.m.Bs[c4 + 0][e] = bReg[p].x;
            u.m.Bs[c4 + 1][e] = bReg[p].y;
            u.m.Bs[c4 + 2][e] = bReg[p].z;
            u.m.Bs[c4 + 3][e] = bReg[p].w;
        }
        __syncthreads();

        // prefetch next tile while computing this one
        if (kt < 224) {
            #pragma unroll
            for (int s = 0; s < 4; ++s) {
                int idx = tid + s * 256;
                int row = idx >> 3;
                int c4 = (idx & 7) * 4;
                aReg[s] = *(const float4*)&hist[(rowBase + row) * 256 + kt + 32 + c4];
            }
            #pragma unroll
            for (int p = 0; p < 8; ++p) {
                int e = (tid >> 3) + p * 32;
                int c4 = (tid & 7) * 4;
                bReg[p] = *(const float4*)&W[(size_t)e * 256 + kt + 32 + c4];
            }
        }

        #pragma unroll 2
        for (int k = 0; k < 32; ++k) {
            float a[8];
            #pragma unroll
            for (int i = 0; i < 8; ++i) a[i] = u.m.At[k][tr + 16 * i];
            const float2* brow = (const float2*)u.m.Bs[k];
            #pragma unroll
            for (int jj = 0; jj < 8; ++jj) {
                float2 bv = brow[tc + 16 * jj];   // e = 2tc + 32jj (+1)
                #pragma unroll
                for (int i = 0; i < 8; ++i) {
                    acc[i][2 * jj]     += a[i] * bv.x;
                    acc[i][2 * jj + 1] += a[i] * bv.y;
                }
            }
        }
        __syncthreads();
    }

    // epilogue: two 64-row halves; logits[k][l] = sum_e tanh(proj)[l][e]*cc[k][e]
    const int lk = tid >> 3;   // 0..31
    const int lg = tid & 7;    // 0..7
    #pragma unroll
    for (int h = 0; h < 2; ++h) {
        // write proj half to LDS (rows tr+16*i4, i = 4h+i4)
        #pragma unroll
        for (int i4 = 0; i4 < 4; ++i4) {
            int i = 4 * h + i4;
            #pragma unroll
            for (int j = 0; j < 16; ++j) {
                int e = 32 * (j >> 1) + 2 * tc + (j & 1);
                u.e.Pj[tr + 16 * i4][e] = tanh_fast(acc[i][j]);
            }
        }
        __syncthreads();

        float lacc[8];
        #pragma unroll
        for (int j = 0; j < 8; ++j) lacc[j] = 0.0f;

        for (int et = 0; et < 8; ++et) {
            {
                int k2 = tid >> 3;
                int c4 = (tid & 7) * 4;
                float4 v = *(const float4*)&cc[(size_t)k2 * 256 + et * 32 + c4];
                *(float4*)&u.e.Cs[k2][c4] = v;
            }
            __syncthreads();
            #pragma unroll
            for (int eq = 0; eq < 8; ++eq) {
                float4 c4 = *(const float4*)&u.e.Cs[lk][eq * 4];
                #pragma unroll
                for (int jl = 0; jl < 8; ++jl) {
                    float4 p4 = *(const float4*)&u.e.Pj[lg + 8 * jl][et * 32 + eq * 4];
                    lacc[jl] += p4.x * c4.x + p4.y * c4.y + p4.z * c4.z + p4.w * c4.w;
                }
            }
            __syncthreads();
        }
        #pragma unroll
        for (int jl = 0; jl < 8; ++jl) {
            size_t r = rowBase + 64 * h + lg + 8 * jl;
            int b = (int)(r / 100);
            int l = (int)(r - (size_t)b * 100);
            logits[(size_t)b * 3200 + lk * 100 + l] = lacc[jl];
        }
    }
}

// K2: per-batch fused mask+softmax -> interests -> aw -> top-k -> user
__global__ __launch_bounds__(256, 2)
void k_attn(const float* __restrict__ hist, const float* __restrict__ cand,
            const int* __restrict__ numi, const int* __restrict__ catc,
            const float* __restrict__ logits, float* __restrict__ out)
{
    __shared__ float wT[100][36];     // weights transposed [l][k]
    __shared__ float ints[32][260];   // interests [k][d]
    __shared__ float cands[16][260];  // cand [n][d]
    __shared__ float aws[16][36];
    __shared__ float maw[16][36];

    const int tid = threadIdx.x;
    const int b = blockIdx.x;
    const int num = numi[b];

    for (int idx = tid; idx < 3200; idx += 256) {
        int k = idx / 100;
        int l = idx - k * 100;
        wT[l][k] = logits[(size_t)b * 3200 + idx];
    }
    #pragma unroll
    for (int s = 0; s < 4; ++s) {
        int idx = tid + s * 256;
        int n = idx >> 6;
        int c4 = (idx & 63) * 4;
        *(float4*)&cands[n][c4] = *(const float4*)&cand[((size_t)b * 16 + n) * 256 + c4];
    }
    __syncthreads();

    // masked softmax over l, 8 lanes per k-row
    {
        const int k = tid >> 3;
        const int lg = tid & 7;
        const bool valid = k < num;
        float vals[13];
        float m = -INFINITY;
        #pragma unroll
        for (int i = 0; i < 13; ++i) {
            int l = lg + 8 * i;
            if (l < 100) {
                float v = valid ? wT[l][k] : NEGV;
                vals[i] = v;
                m = fmaxf(m, v);
            }
        }
        #pragma unroll
        for (int off = 1; off < 8; off <<= 1)
            m = fmaxf(m, __shfl_xor(m, off, 8));
        float s = 0.0f;
        #pragma unroll
        for (int i = 0; i < 13; ++i) {
            int l = lg + 8 * i;
            if (l < 100) {
                float e = expf(vals[i] - m);
                s += e;
                wT[l][k] = e;
            }
        }
        #pragma unroll
        for (int off = 1; off < 8; off <<= 1)
            s += __shfl_xor(s, off, 8);
        float inv = 1.0f / s;
        #pragma unroll
        for (int i = 0; i < 13; ++i) {
            int l = lg + 8 * i;
            if (l < 100) wT[l][k] *= inv;
        }
    }
    __syncthreads();

    // interests[k][d] = sum_l w[k][l] * hist[b][l][d]; thread owns d
    {
        const int d = tid;
        float acc[32];
        #pragma unroll
        for (int k = 0; k < 32; ++k) acc[k] = 0.0f;
        for (int l = 0; l < 100; ++l) {
            float h = hist[((size_t)b * 100 + l) * 256 + d];
            const float4* wrow = (const float4*)wT[l];
            #pragma unroll
            for (int kq = 0; kq < 8; ++kq) {
                float4 w4 = wrow[kq];
                acc[4 * kq + 0] += w4.x * h;
                acc[4 * kq + 1] += w4.y * h;
                acc[4 * kq + 2] += w4.z * h;
                acc[4 * kq + 3] += w4.w * h;
            }
        }
        #pragma unroll
        for (int k = 0; k < 32; ++k) ints[k][d] = acc[k];
    }
    __syncthreads();

    // aw[n][k] = interests[k] . cand[n]
    {
        const int k = tid & 31;
        const int n1 = tid >> 5;   // 0..7
        float s1 = 0.0f, s2 = 0.0f;
        const float4* irow = (const float4*)ints[k];
        const float4* c1 = (const float4*)cands[n1];
        const float4* c2 = (const float4*)cands[n1 + 8];
        for (int q = 0; q < 64; ++q) {
            float4 iv = irow[q];
            float4 a = c1[q];
            float4 c = c2[q];
            s1 += iv.x * a.x + iv.y * a.y + iv.z * a.z + iv.w * a.w;
            s2 += iv.x * c.x + iv.y * c.y + iv.z * c.z + iv.w * c.w;
        }
        aws[n1][k] = s1;
        aws[n1 + 8][k] = s2;
    }
    __syncthreads();

    // stable descending rank + dyn_K mask
    {
        int c = catc[b];
        int dynK = 32 - __clz(2 * c - 1);   // = clip(ceil(log2(2c)),1,32) for c in [1,20]
        const int k = tid & 31;
        const int n1 = tid >> 5;
        #pragma unroll
        for (int h = 0; h < 2; ++h) {
            int n = n1 + 8 * h;
            float a = aws[n][k];
            int cnt = 0;
            #pragma unroll
            for (int j = 0; j < 32; ++j) {
                float aj = aws[n][j];
                cnt += (aj > a) || (aj == a && j < k);
            }
            maw[n][k] = (cnt < dynK) ? a : 0.0f;
        }
    }
    __syncthreads();

    // user[n][d] = sum_k maw[n][k] * interests[k][d]
    {
        const int dd = tid & 63;
        const int ng = tid >> 6;
        float4 acc4[4];
        #pragma unroll
        for (int nn = 0; nn < 4; ++nn) { acc4[nn].x = acc4[nn].y = acc4[nn].z = acc4[nn].w = 0.0f; }
        for (int k = 0; k < 32; ++k) {
            float4 iv = *(const float4*)&ints[k][4 * dd];
            #pragma unroll
            for (int nn = 0; nn < 4; ++nn) {
                float m = maw[4 * ng + nn][k];
                acc4[nn].x += m * iv.x;
                acc4[nn].y += m * iv.y;
                acc4[nn].z += m * iv.z;
                acc4[nn].w += m * iv.w;
            }
        }
        #pragma unroll
        for (int nn = 0; nn < 4; ++nn) {
            *(float4*)&out[((size_t)b * 16 + 4 * ng + nn) * 256 + 4 * dd] = acc4[nn];
        }
    }
}

extern "C" void kernel_launch(void* const* d_in, const int* in_sizes, int n_in,
                              void* d_out, int out_size, void* d_ws, size_t ws_size,
                              hipStream_t stream) {
    const float* hist = (const float*)d_in[0];
    const float* cand = (const float*)d_in[2];
    const int*   numi = (const int*)d_in[3];
    const int*   catc = (const int*)d_in[4];
    const float* W    = (const float*)d_in[5];
    const float* cc   = (const float*)d_in[6];
    float* out = (float*)d_out;
    float* logits = (float*)d_ws;   // 2048*32*100*4 = 26,214,400 B

    k_proj_logits<<<1600, 256, 0, stream>>>(hist, W, cc, logits);
    k_attn<<<2048, 256, 0, stream>>>(hist, cand, numi, catc, logits, out);
}

// Round 3
// 276.235 us; speedup vs baseline: 2.4750x; 2.3042x over previous
//
#include <hip/hip_runtime.h>
#include <math.h>

#define NEGV (-1e9f)

typedef _Float16 half8 __attribute__((ext_vector_type(8)));
typedef _Float16 half4 __attribute__((ext_vector_type(4)));
typedef float f32x4 __attribute__((ext_vector_type(4)));

// Shapes: BS=2048, L=100, D=256, N=16, K=32
// K1: M = BS*L = 204800 rows, BM=128 -> 1600 blocks, 256 thr (4 waves 2x2)
// wave tile 64 rows x 128 e; acc[4 rowtiles][8 coltiles] of f32x4 (C-layout:
// col = lane&15, row = (lane>>4)*4 + i  [m89-verified, dtype-independent])

__device__ inline float tanh_fast(float x) {
    float t = __expf(2.0f * x);
    float r = __builtin_amdgcn_rcpf(t + 1.0f);
    return fmaf(-2.0f, r, 1.0f);
}

__device__ inline void split4(const float4 v, half4& h, half4& m) {
    const float* p = (const float*)&v;
    #pragma unroll
    for (int q = 0; q < 4; ++q) {
        float x = p[q];
        _Float16 hi = (_Float16)x;
        float res = x - (float)hi;   // exact (Sterbenz)
        h[q] = hi;
        m[q] = (_Float16)res;
    }
}

__device__ inline void split8(const f32x4 a, const f32x4 b, half8& h, half8& m) {
    #pragma unroll
    for (int q = 0; q < 4; ++q) {
        float x = a[q];
        _Float16 hi = (_Float16)x;
        h[q] = hi; m[q] = (_Float16)(x - (float)hi);
    }
    #pragma unroll
    for (int q = 0; q < 4; ++q) {
        float x = b[q];
        _Float16 hi = (_Float16)x;
        h[4+q] = hi; m[4+q] = (_Float16)(x - (float)hi);
    }
}

__global__ __launch_bounds__(256, 2)
void k_proj_logits(const float* __restrict__ hist, const float* __restrict__ W,
                   const float* __restrict__ cc, float* __restrict__ logits)
{
    // LDS union: main { Af 16KB (2 spl x 8 rt x 64 slot x half8),
    //                   Bf 32KB (2 spl x 16 ct x 64 slot x half8) }
    //            epi  { Pj float[128][68] = 34816 B }
    __shared__ __align__(16) char smem[49152];
    _Float16* Af = (_Float16*)smem;             // idx = spl*4096 + rt*512 + slot*8 + j
    _Float16* Bf = (_Float16*)(smem + 16384);   // idx = spl*8192 + ct*512 + slot*8 + j
    float (*Pj)[68] = (float(*)[68])smem;

    const int tid  = threadIdx.x;
    const int lane = tid & 63;
    const int w    = tid >> 6;       // wave 0..3
    const int wr   = w >> 1, wc = w & 1;
    const int g    = lane >> 4;      // k-group 0..3
    const int r    = lane & 15;      // row (A) / col (B) within 16-tile
    const size_t rowBase = (size_t)blockIdx.x * 128;

    f32x4 acc[4][8];
    #pragma unroll
    for (int i = 0; i < 4; ++i)
        #pragma unroll
        for (int j = 0; j < 8; ++j) acc[i][j] = (f32x4)(0.0f);

    // staging decode (per-thread constants)
    const int aRow = tid >> 3;              // 0..31 (+32s)
    const int c4   = (tid & 7) * 4;         // k-offset 0..28
    const int sg   = c4 >> 3;               // frag k-group of this stage thread
    const int sj   = c4 & 7;                // j-offset (0 or 4)

    float4 aReg[4], bReg[8];
    #pragma unroll
    for (int s = 0; s < 4; ++s)
        aReg[s] = *(const float4*)&hist[(rowBase + aRow + 32 * s) * 256 + c4];
    #pragma unroll
    for (int p = 0; p < 8; ++p)
        bReg[p] = *(const float4*)&W[(size_t)((tid >> 3) + 32 * p) * 256 + c4];

    for (int kt = 0; kt < 256; kt += 32) {
        __syncthreads();   // previous compute done reading LDS
        // commit A splits: slot(rt=row>>4, g=sg, r=row&15), j=sj..sj+3
        #pragma unroll
        for (int s = 0; s < 4; ++s) {
            int row = aRow + 32 * s;
            half4 h, m;
            split4(aReg[s], h, m);
            int base = (row >> 4) * 512 + sg * 128 + (row & 15) * 8 + sj;
            *(half4*)&Af[base]        = h;
            *(half4*)&Af[4096 + base] = m;
        }
        // commit B splits: slot(ct=e>>4, g=sg, c=e&15)
        #pragma unroll
        for (int p = 0; p < 8; ++p) {
            int e = (tid >> 3) + 32 * p;
            half4 h, m;
            split4(bReg[p], h, m);
            int base = (e >> 4) * 512 + sg * 128 + (e & 15) * 8 + sj;
            *(half4*)&Bf[base]        = h;
            *(half4*)&Bf[8192 + base] = m;
        }
        // prefetch next k-tile (overlaps with compute)
        if (kt < 224) {
            #pragma unroll
            for (int s = 0; s < 4; ++s)
                aReg[s] = *(const float4*)&hist[(rowBase + aRow + 32 * s) * 256 + kt + 32 + c4];
            #pragma unroll
            for (int p = 0; p < 8; ++p)
                bReg[p] = *(const float4*)&W[(size_t)((tid >> 3) + 32 * p) * 256 + kt + 32 + c4];
        }
        __syncthreads();

        // A frags for this wave's 4 row-tiles (lane-linear: addr = 16*(rt*64+lane))
        half8 Ah[4], Am[4];
        #pragma unroll
        for (int rt = 0; rt < 4; ++rt) {
            int rtg = wr * 4 + rt;
            Ah[rt] = *(half8*)&Af[rtg * 512 + lane * 8];
            Am[rt] = *(half8*)&Af[4096 + rtg * 512 + lane * 8];
        }
        #pragma unroll
        for (int ct = 0; ct < 8; ++ct) {
            int ctg = wc * 8 + ct;
            half8 Bh = *(half8*)&Bf[ctg * 512 + lane * 8];
            half8 Bm = *(half8*)&Bf[8192 + ctg * 512 + lane * 8];
            #pragma unroll
            for (int rt = 0; rt < 4; ++rt) {
                acc[rt][ct] = __builtin_amdgcn_mfma_f32_16x16x32_f16(Ah[rt], Bh, acc[rt][ct], 0, 0, 0);
                acc[rt][ct] = __builtin_amdgcn_mfma_f32_16x16x32_f16(Ah[rt], Bm, acc[rt][ct], 0, 0, 0);
                acc[rt][ct] = __builtin_amdgcn_mfma_f32_16x16x32_f16(Am[rt], Bh, acc[rt][ct], 0, 0, 0);
                acc[rt][ct] = __builtin_amdgcn_mfma_f32_16x16x32_f16(Am[rt], Bm, acc[rt][ct], 0, 0, 0);
            }
        }
    }

    // ---- epilogue: tanh -> Pj (fp32, e-chunks of 64) -> logits = Pj . cc^T (split MFMA)
    f32x4 acc2[2][2];
    #pragma unroll
    for (int i = 0; i < 2; ++i)
        #pragma unroll
        for (int j = 0; j < 2; ++j) acc2[i][j] = (f32x4)(0.0f);

    #pragma unroll
    for (int ec = 0; ec < 4; ++ec) {
        __syncthreads();   // LDS free (union reuse / prev chunk reads done)
        if (wc == (ec >> 1)) {
            #pragma unroll
            for (int rt = 0; rt < 4; ++rt) {
                #pragma unroll
                for (int c4i = 0; c4i < 4; ++c4i) {
                    int ctm = (ec & 1) * 4 + c4i;
                    f32x4 t = acc[rt][ctm];
                    int el = c4i * 16 + r;
                    int rb = 64 * wr + rt * 16 + g * 4;
                    #pragma unroll
                    for (int i = 0; i < 4; ++i)
                        Pj[rb + i][el] = tanh_fast(t[i]);
                }
            }
        }
        __syncthreads();
        #pragma unroll
        for (int ks = 0; ks < 2; ++ks) {
            half8 Ah2[2], Am2[2];
            #pragma unroll
            for (int rt2 = 0; rt2 < 2; ++rt2) {
                const float* src = &Pj[32 * w + rt2 * 16 + r][ks * 32 + g * 8];
                f32x4 p0 = *(const f32x4*)src;
                f32x4 p1 = *(const f32x4*)(src + 4);
                split8(p0, p1, Ah2[rt2], Am2[rt2]);
            }
            #pragma unroll
            for (int ct = 0; ct < 2; ++ct) {
                const float* csrc = &cc[(size_t)(ct * 16 + r) * 256 + 64 * ec + ks * 32 + g * 8];
                f32x4 q0 = *(const f32x4*)csrc;
                f32x4 q1 = *(const f32x4*)(csrc + 4);
                half8 Bh, Bm;
                split8(q0, q1, Bh, Bm);
                #pragma unroll
                for (int rt2 = 0; rt2 < 2; ++rt2) {
                    acc2[rt2][ct] = __builtin_amdgcn_mfma_f32_16x16x32_f16(Ah2[rt2], Bh, acc2[rt2][ct], 0, 0, 0);
                    acc2[rt2][ct] = __builtin_amdgcn_mfma_f32_16x16x32_f16(Ah2[rt2], Bm, acc2[rt2][ct], 0, 0, 0);
                    acc2[rt2][ct] = __builtin_amdgcn_mfma_f32_16x16x32_f16(Am2[rt2], Bh, acc2[rt2][ct], 0, 0, 0);
                    acc2[rt2][ct] = __builtin_amdgcn_mfma_f32_16x16x32_f16(Am2[rt2], Bm, acc2[rt2][ct], 0, 0, 0);
                }
            }
        }
    }
    // store logits[grow][k], grow-major (coalesced; K2 loads this layout)
    #pragma unroll
    for (int rt2 = 0; rt2 < 2; ++rt2)
        #pragma unroll
        for (int ct = 0; ct < 2; ++ct)
            #pragma unroll
            for (int i = 0; i < 4; ++i) {
                size_t grow = rowBase + 32 * w + rt2 * 16 + g * 4 + i;
                logits[grow * 32 + ct * 16 + r] = acc2[rt2][ct][i];
            }
}

// K2: per-batch fused mask+softmax -> interests -> aw -> top-k -> user
__global__ __launch_bounds__(256, 2)
void k_attn(const float* __restrict__ hist, const float* __restrict__ cand,
            const int* __restrict__ numi, const int* __restrict__ catc,
            const float* __restrict__ logits, float* __restrict__ out)
{
    __shared__ float wT[100][36];     // weights [l][k]
    __shared__ float ints[32][260];   // interests [k][d]
    __shared__ float cands[16][260];  // cand [n][d]
    __shared__ float aws[16][36];
    __shared__ float maw[16][36];

    const int tid = threadIdx.x;
    const int b = blockIdx.x;
    const int num = numi[b];

    // logits stored [b*100+l][k] -> coalesced load
    for (int idx = tid; idx < 3200; idx += 256) {
        int l = idx >> 5;
        int k = idx & 31;
        wT[l][k] = logits[(size_t)b * 3200 + idx];
    }
    #pragma unroll
    for (int s = 0; s < 4; ++s) {
        int idx = tid + s * 256;
        int n = idx >> 6;
        int c4 = (idx & 63) * 4;
        *(float4*)&cands[n][c4] = *(const float4*)&cand[((size_t)b * 16 + n) * 256 + c4];
    }
    __syncthreads();

    // masked softmax over l, 8 lanes per k-row
    {
        const int k = tid >> 3;
        const int lg = tid & 7;
        const bool valid = k < num;
        float vals[13];
        float m = -INFINITY;
        #pragma unroll
        for (int i = 0; i < 13; ++i) {
            int l = lg + 8 * i;
            if (l < 100) {
                float v = valid ? wT[l][k] : NEGV;
                vals[i] = v;
                m = fmaxf(m, v);
            }
        }
        #pragma unroll
        for (int off = 1; off < 8; off <<= 1)
            m = fmaxf(m, __shfl_xor(m, off, 8));
        float s = 0.0f;
        #pragma unroll
        for (int i = 0; i < 13; ++i) {
            int l = lg + 8 * i;
            if (l < 100) {
                float e = expf(vals[i] - m);
                s += e;
                wT[l][k] = e;
            }
        }
        #pragma unroll
        for (int off = 1; off < 8; off <<= 1)
            s += __shfl_xor(s, off, 8);
        float inv = 1.0f / s;
        #pragma unroll
        for (int i = 0; i < 13; ++i) {
            int l = lg + 8 * i;
            if (l < 100) wT[l][k] *= inv;
        }
    }
    __syncthreads();

    // interests[k][d] = sum_l w[k][l] * hist[b][l][d]; thread owns d
    {
        const int d = tid;
        float acc[32];
        #pragma unroll
        for (int k = 0; k < 32; ++k) acc[k] = 0.0f;
        for (int l = 0; l < 100; ++l) {
            float h = hist[((size_t)b * 100 + l) * 256 + d];
            const float4* wrow = (const float4*)wT[l];
            #pragma unroll
            for (int kq = 0; kq < 8; ++kq) {
                float4 w4 = wrow[kq];
                acc[4 * kq + 0] += w4.x * h;
                acc[4 * kq + 1] += w4.y * h;
                acc[4 * kq + 2] += w4.z * h;
                acc[4 * kq + 3] += w4.w * h;
            }
        }
        #pragma unroll
        for (int k = 0; k < 32; ++k) ints[k][d] = acc[k];
    }
    __syncthreads();

    // aw[n][k] = interests[k] . cand[n]
    {
        const int k = tid & 31;
        const int n1 = tid >> 5;
        float s1 = 0.0f, s2 = 0.0f;
        const float4* irow = (const float4*)ints[k];
        const float4* c1 = (const float4*)cands[n1];
        const float4* c2 = (const float4*)cands[n1 + 8];
        for (int q = 0; q < 64; ++q) {
            float4 iv = irow[q];
            float4 a = c1[q];
            float4 c = c2[q];
            s1 += iv.x * a.x + iv.y * a.y + iv.z * a.z + iv.w * a.w;
            s2 += iv.x * c.x + iv.y * c.y + iv.z * c.z + iv.w * c.w;
        }
        aws[n1][k] = s1;
        aws[n1 + 8][k] = s2;
    }
    __syncthreads();

    // stable descending rank + dyn_K mask
    {
        int c = catc[b];
        int dynK = 32 - __clz(2 * c - 1);   // clip(ceil(log2(2c)),1,32) for c in [1,20]
        const int k = tid & 31;
        const int n1 = tid >> 5;
        #pragma unroll
        for (int h = 0; h < 2; ++h) {
            int n = n1 + 8 * h;
            float a = aws[n][k];
            int cnt = 0;
            #pragma unroll
            for (int j = 0; j < 32; ++j) {
                float aj = aws[n][j];
                cnt += (aj > a) || (aj == a && j < k);
            }
            maw[n][k] = (cnt < dynK) ? a : 0.0f;
        }
    }
    __syncthreads();

    // user[n][d] = sum_k maw[n][k] * interests[k][d]
    {
        const int dd = tid & 63;
        const int ng = tid >> 6;
        float4 acc4[4];
        #pragma unroll
        for (int nn = 0; nn < 4; ++nn) { acc4[nn].x = acc4[nn].y = acc4[nn].z = acc4[nn].w = 0.0f; }
        for (int k = 0; k < 32; ++k) {
            float4 iv = *(const float4*)&ints[k][4 * dd];
            #pragma unroll
            for (int nn = 0; nn < 4; ++nn) {
                float m = maw[4 * ng + nn][k];
                acc4[nn].x += m * iv.x;
                acc4[nn].y += m * iv.y;
                acc4[nn].z += m * iv.z;
                acc4[nn].w += m * iv.w;
            }
        }
        #pragma unroll
        for (int nn = 0; nn < 4; ++nn) {
            *(float4*)&out[((size_t)b * 16 + 4 * ng + nn) * 256 + 4 * dd] = acc4[nn];
        }
    }
}

extern "C" void kernel_launch(void* const* d_in, const int* in_sizes, int n_in,
                              void* d_out, int out_size, void* d_ws, size_t ws_size,
                              hipStream_t stream) {
    const float* hist = (const float*)d_in[0];
    const float* cand = (const float*)d_in[2];
    const int*   numi = (const int*)d_in[3];
    const int*   catc = (const int*)d_in[4];
    const float* W    = (const float*)d_in[5];
    const float* cc   = (const float*)d_in[6];
    float* out = (float*)d_out;
    float* logits = (float*)d_ws;   // 204800*32*4 = 26,214,400 B

    k_proj_logits<<<1600, 256, 0, stream>>>(hist, W, cc, logits);
    k_attn<<<2048, 256, 0, stream>>>(hist, cand, numi, catc, logits, out);
}

// Round 4
// 257.035 us; speedup vs baseline: 2.6599x; 1.0747x over previous
//
#include <hip/hip_runtime.h>
#include <math.h>

#define NEGV (-1e9f)

typedef _Float16 half8 __attribute__((ext_vector_type(8)));
typedef float f32x4 __attribute__((ext_vector_type(4)));

// Shapes: BS=2048, L=100, D=256, N=16, K=32
// K1: M = 204800 rows, BM=128 -> 1600 blocks, 256 thr (4 waves, 2x2)
// wave tile 64 rows x 128 e; 3-product f16-split MFMA (hh, hm, mh)

__device__ inline float tanh_fast(float x) {
    float t = __expf(2.0f * x);
    float r = __builtin_amdgcn_rcpf(t + 1.0f);
    return fmaf(-2.0f, r, 1.0f);
}

__device__ inline void split8(const float4 a, const float4 b, half8& h, half8& m) {
    const float* pa = (const float*)&a;
    const float* pb = (const float*)&b;
    #pragma unroll
    for (int q = 0; q < 4; ++q) {
        float x = pa[q];
        _Float16 hi = (_Float16)x;
        h[q] = hi; m[q] = (_Float16)(x - (float)hi);
    }
    #pragma unroll
    for (int q = 0; q < 4; ++q) {
        float x = pb[q];
        _Float16 hi = (_Float16)x;
        h[4+q] = hi; m[4+q] = (_Float16)(x - (float)hi);
    }
}

__device__ inline void gload_lds16(const void* g, void* lds) {
    __builtin_amdgcn_global_load_lds(
        (const __attribute__((address_space(1))) unsigned int*)g,
        (__attribute__((address_space(3))) unsigned int*)lds, 16, 0, 0);
}

// Pre-split W into MFMA frag layout: Wf[kt][split][ct][lane] as half8 (16B units)
// slot: kt = s>>10, ct = (s>>6)&15, lane = s&63; e = ct*16+(lane&15), g = lane>>4
__global__ __launch_bounds__(256)
void k_prep(const float* __restrict__ W, half8* __restrict__ Wf)
{
    int slot = blockIdx.x * 256 + threadIdx.x;   // 8192 slots
    int kt = slot >> 10;
    int ct = (slot >> 6) & 15;
    int lane = slot & 63;
    int e = ct * 16 + (lane & 15);
    int g = lane >> 4;
    const float* src = &W[(size_t)e * 256 + kt * 32 + g * 8];
    float4 a = *(const float4*)src;
    float4 b = *(const float4*)(src + 4);
    half8 h, m;
    split8(a, b, h, m);
    Wf[((kt * 2 + 0) * 16 + ct) * 64 + lane] = h;
    Wf[((kt * 2 + 1) * 16 + ct) * 64 + lane] = m;
}

__global__ __launch_bounds__(256, 2)
void k_proj_logits(const float* __restrict__ hist, const half8* __restrict__ Wf,
                   const float* __restrict__ cc, float* __restrict__ logits)
{
    // LDS: main { Af 16KB: [split][8 rt][64 lane] half8 ; Bf 32KB: [split][16 ct][64] half8 }
    //      epi  { Pj float[128][68] = 34816 B }
    __shared__ __align__(16) char smem[49152];
    _Float16* Af = (_Float16*)smem;             // halfs; h-plane units [0,512), m [512,1024)
    _Float16* Bf = (_Float16*)(smem + 16384);   // halfs; h units [0,1024), m [1024,2048)
    float (*Pj)[68] = (float(*)[68])smem;

    const int tid  = threadIdx.x;
    const int lane = tid & 63;
    const int w    = tid >> 6;       // wave 0..3
    const int wr   = w >> 1, wc = w & 1;
    const int g    = lane >> 4;      // k-octet 0..3
    const int r    = lane & 15;      // row/col within 16-tile
    const size_t rowBase = (size_t)blockIdx.x * 128;

    f32x4 acc[4][8];
    #pragma unroll
    for (int i = 0; i < 4; ++i)
        #pragma unroll
        for (int j = 0; j < 8; ++j) acc[i][j] = (f32x4)(0.0f);

    // A staging: thread owns slots (rt=w, lane) and (rt=w+4, lane)
    // row = rt*16 + r, k-octet g -> 32B contiguous global read
    const float* aSrc0 = &hist[(rowBase + (size_t)(w    ) * 16 + r) * 256 + g * 8];
    const float* aSrc1 = &hist[(rowBase + (size_t)(w + 4) * 16 + r) * 256 + g * 8];

    float4 a00 = *(const float4*)aSrc0;
    float4 a01 = *(const float4*)(aSrc0 + 4);
    float4 a10 = *(const float4*)aSrc1;
    float4 a11 = *(const float4*)(aSrc1 + 4);

    for (int kt = 0; kt < 8; ++kt) {
        __syncthreads();   // previous compute done reading LDS
        // B: async copy 32KB of pre-split W frags for this k-tile
        {
            const char* wsrc = (const char*)Wf + (size_t)kt * 32768 + tid * 16;
            char* ldst = smem + 16384 + (tid & 192) * 16;   // wave-uniform base
            #pragma unroll
            for (int i = 0; i < 8; ++i)
                gload_lds16(wsrc + i * 4096, ldst + i * 4096);
        }
        // A: split + lane-linear b128 writes
        {
            half8 h, m;
            split8(a00, a01, h, m);
            int u = w * 64 + lane;
            *(half8*)&Af[u * 8] = h;
            *(half8*)&Af[(512 + u) * 8] = m;
            split8(a10, a11, h, m);
            u = (w + 4) * 64 + lane;
            *(half8*)&Af[u * 8] = h;
            *(half8*)&Af[(512 + u) * 8] = m;
        }
        // prefetch next A k-tile
        if (kt < 7) {
            int off = (kt + 1) * 32;
            a00 = *(const float4*)(aSrc0 + off);
            a01 = *(const float4*)(aSrc0 + off + 4);
            a10 = *(const float4*)(aSrc1 + off);
            a11 = *(const float4*)(aSrc1 + off + 4);
        }
        __syncthreads();

        half8 Ah[4], Am[4];
        #pragma unroll
        for (int rt = 0; rt < 4; ++rt) {
            int u = (wr * 4 + rt) * 64 + lane;
            Ah[rt] = *(half8*)&Af[u * 8];
            Am[rt] = *(half8*)&Af[(512 + u) * 8];
        }
        #pragma unroll
        for (int ct = 0; ct < 8; ++ct) {
            int ctg = wc * 8 + ct;
            half8 Bh = *(half8*)&Bf[(ctg * 64 + lane) * 8];
            half8 Bm = *(half8*)&Bf[((1024 + ctg * 64 + lane)) * 8];
            #pragma unroll
            for (int rt = 0; rt < 4; ++rt) {
                acc[rt][ct] = __builtin_amdgcn_mfma_f32_16x16x32_f16(Ah[rt], Bh, acc[rt][ct], 0, 0, 0);
                acc[rt][ct] = __builtin_amdgcn_mfma_f32_16x16x32_f16(Ah[rt], Bm, acc[rt][ct], 0, 0, 0);
                acc[rt][ct] = __builtin_amdgcn_mfma_f32_16x16x32_f16(Am[rt], Bh, acc[rt][ct], 0, 0, 0);
            }
        }
    }

    // ---- epilogue: tanh -> Pj (fp32, 4 e-chunks of 64) -> logits = Pj . cc^T (3-prod MFMA)
    f32x4 acc2[2][2];
    #pragma unroll
    for (int i = 0; i < 2; ++i)
        #pragma unroll
        for (int j = 0; j < 2; ++j) acc2[i][j] = (f32x4)(0.0f);

    #pragma unroll
    for (int ec = 0; ec < 4; ++ec) {
        __syncthreads();
        if (wc == (ec >> 1)) {
            #pragma unroll
            for (int rt = 0; rt < 4; ++rt) {
                #pragma unroll
                for (int c4i = 0; c4i < 4; ++c4i) {
                    int ctm = (ec & 1) * 4 + c4i;
                    f32x4 t = acc[rt][ctm];
                    int el = c4i * 16 + r;
                    int rb = 64 * wr + rt * 16 + g * 4;
                    #pragma unroll
                    for (int i = 0; i < 4; ++i)
                        Pj[rb + i][el] = tanh_fast(t[i]);
                }
            }
        }
        __syncthreads();
        #pragma unroll
        for (int ks = 0; ks < 2; ++ks) {
            half8 Ah2[2], Am2[2];
            #pragma unroll
            for (int rt2 = 0; rt2 < 2; ++rt2) {
                const float* src = &Pj[32 * w + rt2 * 16 + r][ks * 32 + g * 8];
                float4 p0 = *(const float4*)src;
                float4 p1 = *(const float4*)(src + 4);
                split8(p0, p1, Ah2[rt2], Am2[rt2]);
            }
            #pragma unroll
            for (int ct = 0; ct < 2; ++ct) {
                const float* csrc = &cc[(size_t)(ct * 16 + r) * 256 + 64 * ec + ks * 32 + g * 8];
                float4 q0 = *(const float4*)csrc;
                float4 q1 = *(const float4*)(csrc + 4);
                half8 Bh, Bm;
                split8(q0, q1, Bh, Bm);
                #pragma unroll
                for (int rt2 = 0; rt2 < 2; ++rt2) {
                    acc2[rt2][ct] = __builtin_amdgcn_mfma_f32_16x16x32_f16(Ah2[rt2], Bh, acc2[rt2][ct], 0, 0, 0);
                    acc2[rt2][ct] = __builtin_amdgcn_mfma_f32_16x16x32_f16(Ah2[rt2], Bm, acc2[rt2][ct], 0, 0, 0);
                    acc2[rt2][ct] = __builtin_amdgcn_mfma_f32_16x16x32_f16(Am2[rt2], Bh, acc2[rt2][ct], 0, 0, 0);
                }
            }
        }
    }
    // store logits[grow][k] (coalesced; K2 loads this layout)
    #pragma unroll
    for (int rt2 = 0; rt2 < 2; ++rt2)
        #pragma unroll
        for (int ct = 0; ct < 2; ++ct)
            #pragma unroll
            for (int i = 0; i < 4; ++i) {
                size_t grow = rowBase + 32 * w + rt2 * 16 + g * 4 + i;
                logits[grow * 32 + ct * 16 + r] = acc2[rt2][ct][i];
            }
}

// K2: per-batch fused mask+softmax -> interests -> aw -> top-k -> user
__global__ __launch_bounds__(256, 3)
void k_attn(const float* __restrict__ hist, const float* __restrict__ cand,
            const int* __restrict__ numi, const int* __restrict__ catc,
            const float* __restrict__ logits, float* __restrict__ out)
{
    __shared__ float wT[100][36];   // weights [l][k]      14400 B
    __shared__ float ib[32][260];   // hist chunks (2x16 rows dbuf) then ints[k][d]  33280 B
    __shared__ float aws[16][36];   //                       2304 B
    __shared__ float maw[16][36];   //                       2304 B  -> total 52288 B (3 blk/CU)

    const int tid = threadIdx.x;
    const int b = blockIdx.x;
    const int num = numi[b];

    // load logits [l][k] layout (contiguous 12.8KB per batch)
    for (int idx = tid; idx < 3200; idx += 256) {
        int l = idx >> 5;
        int k = idx & 31;
        wT[l][k] = logits[(size_t)b * 3200 + idx];
    }
    __syncthreads();

    // masked softmax over l, 8 lanes per k-row
    {
        const int k = tid >> 3;
        const int lg = tid & 7;
        const bool valid = k < num;
        float vals[13];
        float m = -INFINITY;
        #pragma unroll
        for (int i = 0; i < 13; ++i) {
            int l = lg + 8 * i;
            if (l < 100) {
                float v = valid ? wT[l][k] : NEGV;
                vals[i] = v;
                m = fmaxf(m, v);
            }
        }
        #pragma unroll
        for (int off = 1; off < 8; off <<= 1)
            m = fmaxf(m, __shfl_xor(m, off, 8));
        float s = 0.0f;
        #pragma unroll
        for (int i = 0; i < 13; ++i) {
            int l = lg + 8 * i;
            if (l < 100) {
                float e = expf(vals[i] - m);
                s += e;
                wT[l][k] = e;
            }
        }
        #pragma unroll
        for (int off = 1; off < 8; off <<= 1)
            s += __shfl_xor(s, off, 8);
        float inv = 1.0f / s;
        #pragma unroll
        for (int i = 0; i < 13; ++i) {
            int l = lg + 8 * i;
            if (l < 100) wT[l][k] *= inv;
        }
    }
    __syncthreads();

    // interests[k][d] = sum_l w[k][l]*hist[b][l][d]; d = tid; 7 chunks of 16 l-rows,
    // double-buffered in ib rows [parity*16 .. +16), loads issued before compute (T14)
    {
        float acc[32];
        #pragma unroll
        for (int k = 0; k < 32; ++k) acc[k] = 0.0f;

        // stage chunk 0
        #pragma unroll
        for (int s = 0; s < 4; ++s) {
            int idx = tid + s * 256;
            int lp = idx >> 6;
            int c4 = (idx & 63) * 4;
            *(float4*)&ib[lp][c4] = *(const float4*)&hist[((size_t)b * 100 + lp) * 256 + c4];
        }
        __syncthreads();

        for (int c = 0; c < 7; ++c) {
            float4 pre[4];
            if (c < 6) {
                #pragma unroll
                for (int s = 0; s < 4; ++s) {
                    int idx = tid + s * 256;
                    int lp = idx >> 6;
                    int c4 = (idx & 63) * 4;
                    int l = 16 * (c + 1) + lp;
                    pre[s] = (l < 100) ? *(const float4*)&hist[((size_t)b * 100 + l) * 256 + c4]
                                       : float4{0.f, 0.f, 0.f, 0.f};
                }
            }
            int rows = (c == 6) ? 4 : 16;
            const int rb = (c & 1) * 16;
            #pragma unroll 4
            for (int lp = 0; lp < rows; ++lp) {
                float h = ib[rb + lp][tid];
                const float4* wrow = (const float4*)wT[16 * c + lp];
                #pragma unroll
                for (int kq = 0; kq < 8; ++kq) {
                    float4 w4 = wrow[kq];
                    acc[4 * kq + 0] = fmaf(w4.x, h, acc[4 * kq + 0]);
                    acc[4 * kq + 1] = fmaf(w4.y, h, acc[4 * kq + 1]);
                    acc[4 * kq + 2] = fmaf(w4.z, h, acc[4 * kq + 2]);
                    acc[4 * kq + 3] = fmaf(w4.w, h, acc[4 * kq + 3]);
                }
            }
            if (c < 6) {
                const int wb = ((c + 1) & 1) * 16;
                #pragma unroll
                for (int s = 0; s < 4; ++s) {
                    int idx = tid + s * 256;
                    int lp = idx >> 6;
                    int c4 = (idx & 63) * 4;
                    *(float4*)&ib[wb + lp][c4] = pre[s];
                }
            }
            __syncthreads();
        }
        // write interests into ib (chunk reads all done)
        #pragma unroll
        for (int k = 0; k < 32; ++k) ib[k][tid] = acc[k];
    }
    __syncthreads();

    // aw[n][k] = ints[k] . cand[n]; thread = (n = tid&15, kq = tid>>4), k in {kq, kq+16}
    {
        const int n = tid & 15;
        const int kq = tid >> 4;
        const float4* cg = (const float4*)&cand[((size_t)b * 16 + n) * 256];
        const float4* i0 = (const float4*)&ib[kq][0];
        const float4* i1 = (const float4*)&ib[kq + 16][0];
        float s0 = 0.0f, s1 = 0.0f;
        for (int q = 0; q < 64; ++q) {
            float4 cv = cg[q];
            float4 a0 = i0[q];
            float4 a1 = i1[q];
            s0 += a0.x * cv.x + a0.y * cv.y + a0.z * cv.z + a0.w * cv.w;
            s1 += a1.x * cv.x + a1.y * cv.y + a1.z * cv.z + a1.w * cv.w;
        }
        aws[n][kq] = s0;
        aws[n][kq + 16] = s1;
    }
    __syncthreads();

    // stable descending rank + dyn_K mask
    {
        int c = catc[b];
        int dynK = 32 - __clz(2 * c - 1);   // clip(ceil(log2(2c)),1,32) for c in [1,20]
        const int k = tid & 31;
        const int n1 = tid >> 5;
        #pragma unroll
        for (int h = 0; h < 2; ++h) {
            int n = n1 + 8 * h;
            float a = aws[n][k];
            int cnt = 0;
            #pragma unroll
            for (int j = 0; j < 32; ++j) {
                float aj = aws[n][j];
                cnt += (aj > a) || (aj == a && j < k);
            }
            maw[n][k] = (cnt < dynK) ? a : 0.0f;
        }
    }
    __syncthreads();

    // user[n][d] = sum_k maw[n][k] * ints[k][d]
    {
        const int dd = tid & 63;
        const int ng = tid >> 6;
        float4 acc4[4];
        #pragma unroll
        for (int nn = 0; nn < 4; ++nn) { acc4[nn].x = acc4[nn].y = acc4[nn].z = acc4[nn].w = 0.0f; }
        for (int k = 0; k < 32; ++k) {
            float4 iv = *(const float4*)&ib[k][4 * dd];
            #pragma unroll
            for (int nn = 0; nn < 4; ++nn) {
                float m = maw[4 * ng + nn][k];
                acc4[nn].x = fmaf(m, iv.x, acc4[nn].x);
                acc4[nn].y = fmaf(m, iv.y, acc4[nn].y);
                acc4[nn].z = fmaf(m, iv.z, acc4[nn].z);
                acc4[nn].w = fmaf(m, iv.w, acc4[nn].w);
            }
        }
        #pragma unroll
        for (int nn = 0; nn < 4; ++nn) {
            *(float4*)&out[((size_t)b * 16 + 4 * ng + nn) * 256 + 4 * dd] = acc4[nn];
        }
    }
}

extern "C" void kernel_launch(void* const* d_in, const int* in_sizes, int n_in,
                              void* d_out, int out_size, void* d_ws, size_t ws_size,
                              hipStream_t stream) {
    const float* hist = (const float*)d_in[0];
    const float* cand = (const float*)d_in[2];
    const int*   numi = (const int*)d_in[3];
    const int*   catc = (const int*)d_in[4];
    const float* W    = (const float*)d_in[5];
    const float* cc   = (const float*)d_in[6];
    float* out = (float*)d_out;
    float* logits = (float*)d_ws;                 // 26,214,400 B
    const size_t LOG_BYTES = 26214400;
    const size_t WF_BYTES = 262144;               // 8kt x 2spl x 16ct x 64 x 16B
    // W frag scratch: ws tail if it fits, else front of d_out (fully rewritten by k_attn later)
    half8* Wf = (ws_size >= LOG_BYTES + WF_BYTES)
                ? (half8*)((char*)d_ws + LOG_BYTES)
                : (half8*)d_out;

    k_prep<<<32, 256, 0, stream>>>(W, Wf);
    k_proj_logits<<<1600, 256, 0, stream>>>(hist, Wf, cc, logits);
    k_attn<<<2048, 256, 0, stream>>>(hist, cand, numi, catc, logits, out);
}